// Round 1
// baseline (554.856 us; speedup 1.0000x reference)
//
#include <hip/hip_runtime.h>

#define TOK   64
#define NOUT  8192
#define KTOT  8192
#define KQ    7936
#define KFP   256

typedef float f32x4 __attribute__((ext_vector_type(4)));
typedef short s16x8 __attribute__((ext_vector_type(8)));

// f32 -> bf16 round-to-nearest-even via bit trick (no NaN inputs here)
__device__ __forceinline__ unsigned short f2bf(float f) {
    unsigned int u = __float_as_uint(f);
    u += 0x7fffu + ((u >> 16) & 1u);
    return (unsigned short)(u >> 16);
}

// Scatter input columns through inv_col_perm and cast to bf16.
// x_perm[t, inv[j]] = (bf16) input[t, j]  -- then the GEMM uses weights in
// natural (unpermuted) order: cols [0,7936) = w_noised, [7936,8192) = fp_w.
__global__ void permute_cast(const float* __restrict__ inp,
                             const int* __restrict__ invp,
                             unsigned short* __restrict__ xp) {
    int idx = blockIdx.x * blockDim.x + threadIdx.x;   // 64*8192 threads
    int t = idx >> 13;
    int j = idx & (KTOT - 1);
    xp[t * KTOT + invp[j]] = f2bf(inp[idx]);
}

// Fused: w_noised computed in-register from streamed q_w/noise, bf16 MFMA.
// Block = 16 output rows; 8 waves split K (1024 each); LDS tree at end.
__global__ __launch_bounds__(512) void sasut_gemm(
    const unsigned short* __restrict__ xp,   // [64][8192] bf16, permuted input
    const float* __restrict__ qw,            // [8192][7936]
    const float* __restrict__ fpw,           // [8192][256]
    const float* __restrict__ alpha,         // [8192]
    const float* __restrict__ noise,         // [8192][7936]
    const float* __restrict__ bias,          // [8192]
    float* __restrict__ out)                 // [64][8192]
{
    const int tid  = threadIdx.x;
    const int wave = tid >> 6;
    const int lane = tid & 63;
    const int nloc = lane & 15;      // B-fragment row (output col), A-fragment row (token)
    const int quad = lane >> 4;      // k sub-chunk: k = quad*8 + j
    const int nbase = blockIdx.x * 16;
    const int o = nbase + nloc;

    const float a_s  = alpha[o];
    const float c_s  = a_s * (1.0f / 14.0f);   // 0.5 * alpha/QMAX, QMAX=7
    const float na_s = -a_s;

    f32x4 acc[4];
    #pragma unroll
    for (int i = 0; i < 4; ++i) acc[i] = (f32x4){0.f, 0.f, 0.f, 0.f};

    const float* qrow = qw    + (size_t)o * KQ;
    const float* nrow = noise + (size_t)o * KQ;
    const float* frow = fpw   + (size_t)o * KFP;

    const int k0 = wave * (KTOT / 8);          // per-wave K slice: 1024

    for (int s = 0; s < 32; ++s) {             // 32 steps of BK=32
        const int kbase = k0 + s * 32;         // wave-uniform; 7936 % 32 == 0
        const int kk = kbase + quad * 8;
        s16x8 bfrag;
        if (kbase < KQ) {
            f32x4 w0 = *(const f32x4*)(qrow + kk);
            f32x4 w1 = *(const f32x4*)(qrow + kk + 4);
            f32x4 n0 = *(const f32x4*)(nrow + kk);
            f32x4 n1 = *(const f32x4*)(nrow + kk + 4);
            #pragma unroll
            for (int j = 0; j < 8; ++j) {
                float w  = (j < 4) ? w0[j] : w1[j - 4];
                float nz = (j < 4) ? n0[j] : n1[j - 4];
                float t = fmaf(nz, c_s, w);            // w + noise*0.5*delta
                t = (w >= a_s)  ? a_s  : t;
                t = (w <= na_s) ? na_s : t;
                bfrag[j] = (short)f2bf(t);
            }
        } else {
            f32x4 w0 = *(const f32x4*)(frow + (kk - KQ));
            f32x4 w1 = *(const f32x4*)(frow + (kk - KQ) + 4);
            #pragma unroll
            for (int j = 0; j < 8; ++j) {
                float w = (j < 4) ? w0[j] : w1[j - 4];
                bfrag[j] = (short)f2bf(w);
            }
        }
        #pragma unroll
        for (int mt = 0; mt < 4; ++mt) {       // 4 M-tiles cover 64 tokens
            s16x8 afrag = *(const s16x8*)(xp + (size_t)(mt * 16 + nloc) * KTOT + kk);
            acc[mt] = __builtin_amdgcn_mfma_f32_16x16x32_bf16(afrag, bfrag, acc[mt], 0, 0, 0);
        }
    }

    // Cross-wave K-reduction: C/D layout col=lane&15, row=(lane>>4)*4+reg.
    __shared__ float red[8][TOK][16];          // 32 KB
    #pragma unroll
    for (int mt = 0; mt < 4; ++mt)
        #pragma unroll
        for (int r = 0; r < 4; ++r)
            red[wave][mt * 16 + quad * 4 + r][nloc] = acc[mt][r];
    __syncthreads();

    #pragma unroll
    for (int rep = 0; rep < 2; ++rep) {
        int e  = tid + rep * 512;              // 1024 outputs, 512 threads
        int t  = e >> 4;
        int ol = e & 15;
        float s = 0.f;
        #pragma unroll
        for (int w = 0; w < 8; ++w) s += red[w][t][ol];
        out[(size_t)t * NOUT + nbase + ol] = s + bias[nbase + ol];
    }
}

extern "C" void kernel_launch(void* const* d_in, const int* in_sizes, int n_in,
                              void* d_out, int out_size, void* d_ws, size_t ws_size,
                              hipStream_t stream) {
    const float* inp   = (const float*)d_in[0];   // [64][8192]
    const float* qw    = (const float*)d_in[1];   // [8192][7936]
    const float* fpw   = (const float*)d_in[2];   // [8192][256]
    const float* alpha = (const float*)d_in[3];   // [8192][1]
    const float* bias  = (const float*)d_in[4];   // [8192]
    const float* noise = (const float*)d_in[5];   // [8192][7936]
    const int*   invp  = (const int*)d_in[6];     // [8192]
    float* out = (float*)d_out;                   // [64][8192]
    unsigned short* xp = (unsigned short*)d_ws;   // 64*8192 bf16 = 1 MB scratch

    permute_cast<<<(TOK * KTOT) / 256, 256, 0, stream>>>(inp, invp, xp);
    sasut_gemm<<<NOUT / 16, 512, 0, stream>>>(xp, qw, fpw, alpha, noise, bias, out);
}

// Round 2
// 543.486 us; speedup vs baseline: 1.0209x; 1.0209x over previous
//
#include <hip/hip_runtime.h>

#define TOK    64
#define NOUT   8192
#define KTOT   8192
#define KQ     7936
#define KFP    256
#define KSPLIT 2
#define KBLK   (KTOT / KSPLIT)   // 4096 per block
#define BK     128
#define NS     (KBLK / BK)       // 32 steps

typedef float f32x4 __attribute__((ext_vector_type(4)));
typedef short s16x8 __attribute__((ext_vector_type(8)));

__device__ __forceinline__ unsigned short f2bf(float f) {
    unsigned int u = __float_as_uint(f);
    u += 0x7fffu + ((u >> 16) & 1u);
    return (unsigned short)(u >> 16);
}

__device__ __forceinline__ void gload_lds16(const void* g, void* l) {
    __builtin_amdgcn_global_load_lds(
        (const __attribute__((address_space(1))) void*)g,
        (__attribute__((address_space(3))) void*)l, 16, 0, 0);
}

// Fused prep: permute+cast input to bf16 AND init out with bias.
// (64*8192 threads covers both 64x8192 arrays)
__global__ void prep(const float* __restrict__ inp, const int* __restrict__ invp,
                     const float* __restrict__ bias,
                     unsigned short* __restrict__ xp, float* __restrict__ out) {
    int idx = blockIdx.x * blockDim.x + threadIdx.x;
    int j = idx & (KTOT - 1);
    xp[(idx >> 13) * KTOT + invp[j]] = f2bf(inp[idx]);
    out[idx] = bias[j];
}

// Block: 16 output rows x BK=128 K-step, double-buffered LDS staging via
// global_load_lds (1KB contiguous per instr), XOR-swizzled to kill ds_read
// bank conflicts. 8 waves = 4 M-tiles x 2 K-halves; acc = one 16x16 tile.
// K split 2x across blocks; epilogue atomicAdd onto bias-initialized out.
__global__ __launch_bounds__(512) void sasut_gemm(
    const unsigned short* __restrict__ xp,   // [64][8192] bf16 permuted input
    const float* __restrict__ qw,            // [8192][7936]
    const float* __restrict__ fpw,           // [8192][256]
    const float* __restrict__ alpha,         // [8192]
    const float* __restrict__ noise,         // [8192][7936]
    float* __restrict__ out)                 // [64][8192], pre-set to bias
{
    __shared__ __attribute__((aligned(16))) char smem[2 * 16384]; // 2 bufs: q 8KB + n 8KB each
    const int tid  = threadIdx.x;
    const int w    = tid >> 6;
    const int lane = tid & 63;
    const int nloc = lane & 15;     // output col within tile / B-frag row
    const int quad = lane >> 4;
    const int mt   = w & 3;         // M-tile (tokens mt*16..+16)
    const int h    = w >> 2;        // K-half within BK step
    const int ct   = blockIdx.x & 511;
    const int sp   = blockIdx.x >> 9;
    const int nbase = ct * 16;
    const int koff  = sp * KBLK;

    const float a_s  = alpha[nbase + nloc];
    const float c_s  = a_s * (1.0f / 14.0f);   // 0.5 * alpha / QMAX (QMAX=7)
    const float na_s = -a_s;

    // --- staging mapping: wave w stages rows {2w, 2w+1}; lane covers 16B chunk
    const int sr = 2 * w + (lane >> 5);          // staged row (0..15)
    const int gc = (lane & 31) ^ (sr & 7);       // XOR-swizzled global chunk
    const size_t qrow_off = (size_t)(nbase + sr) * KQ + gc * 4;
    const size_t frow_off = (size_t)(nbase + sr) * KFP + gc * 4;

    const int sw = nloc & 7;                     // consume-side swizzle

    // A-fragment source: token row mt*16+nloc, k window h*64 + i*32 + quad*8
    const unsigned short* xrow =
        xp + (size_t)(mt * 16 + nloc) * KTOT + koff + h * 64 + quad * 8;

    auto stage = [&](int s, int buf) {
        const int kb = koff + s * BK;            // block-uniform
        char* ldq = smem + buf * 16384 + w * 1024;
        if (kb < KQ) {
            gload_lds16(qw + qrow_off + kb, ldq);
            gload_lds16(noise + qrow_off + kb, ldq + 8192);
        } else {
            gload_lds16(fpw + frow_off + (kb - KQ), ldq);
        }
    };

    f32x4 acc = {0.f, 0.f, 0.f, 0.f};

    stage(0, 0);
    s16x8 af0 = *(const s16x8*)(xrow);
    s16x8 af1 = *(const s16x8*)(xrow + 32);
    __syncthreads();                              // drains staging vmcnt

    #pragma unroll 2
    for (int s = 0; s < NS; ++s) {
        const int nxt = s + 1;
        s16x8 nf0 = af0, nf1 = af1;
        if (nxt < NS) {
            stage(nxt, nxt & 1);                  // async into other buffer
            nf0 = *(const s16x8*)(xrow + nxt * BK);
            nf1 = *(const s16x8*)(xrow + nxt * BK + 32);
        }
        // consume step s from buffer s&1
        const float* qb_ = (const float*)(smem + (s & 1) * 16384) + nloc * 128;
        const float* nb_ = qb_ + 2048;
        const bool isfp = (koff + s * BK) >= KQ;  // steps never straddle KQ
        #pragma unroll
        for (int i = 0; i < 2; ++i) {
            const int kt = h * 64 + i * 32;
            const int c0 = (kt >> 2) + quad * 2;  // 16B chunk index in row
            f32x4 qa = *(const f32x4*)(qb_ + ((c0 ^ sw) << 2));
            f32x4 qc = *(const f32x4*)(qb_ + (((c0 + 1) ^ sw) << 2));
            s16x8 bf;
            if (!isfp) {
                f32x4 na = *(const f32x4*)(nb_ + ((c0 ^ sw) << 2));
                f32x4 nc = *(const f32x4*)(nb_ + (((c0 + 1) ^ sw) << 2));
                #pragma unroll
                for (int j = 0; j < 8; ++j) {
                    float wv = (j < 4) ? qa[j] : qc[j - 4];
                    float nz = (j < 4) ? na[j] : nc[j - 4];
                    float t = fmaf(nz, c_s, wv);
                    t = (wv >= a_s)  ? a_s  : t;
                    t = (wv <= na_s) ? na_s : t;
                    bf[j] = (short)f2bf(t);
                }
            } else {
                #pragma unroll
                for (int j = 0; j < 8; ++j) {
                    float wv = (j < 4) ? qa[j] : qc[j - 4];
                    bf[j] = (short)f2bf(wv);
                }
            }
            acc = __builtin_amdgcn_mfma_f32_16x16x32_bf16(
                (i == 0) ? af0 : af1, bf, acc, 0, 0, 0);
        }
        __syncthreads();   // staging for s+1 drained + buf s&1 free for s+2
        af0 = nf0; af1 = nf1;
    }

    // Cross-h reduction in LDS (reuse buffer 0 region), then atomicAdd.
    float* red = (float*)smem;                    // [8][16][17] = 8.7 KB
    #pragma unroll
    for (int r = 0; r < 4; ++r)
        red[(w * 16 + quad * 4 + r) * 17 + nloc] = acc[r];
    __syncthreads();
    #pragma unroll
    for (int rep = 0; rep < 2; ++rep) {
        int e   = tid + rep * 512;                // 4 mtiles x 16 x 16 = 1024
        int m   = e >> 8;
        int tl  = (e >> 4) & 15;
        int col = e & 15;
        float v = red[(m * 16 + tl) * 17 + col] +
                  red[((m + 4) * 16 + tl) * 17 + col];
        atomicAdd(out + (size_t)(m * 16 + tl) * NOUT + nbase + col, v);
    }
}

extern "C" void kernel_launch(void* const* d_in, const int* in_sizes, int n_in,
                              void* d_out, int out_size, void* d_ws, size_t ws_size,
                              hipStream_t stream) {
    const float* inp   = (const float*)d_in[0];
    const float* qw    = (const float*)d_in[1];
    const float* fpw   = (const float*)d_in[2];
    const float* alpha = (const float*)d_in[3];
    const float* bias  = (const float*)d_in[4];
    const float* noise = (const float*)d_in[5];
    const int*   invp  = (const int*)d_in[6];
    float* out = (float*)d_out;
    unsigned short* xp = (unsigned short*)d_ws;   // 1 MB scratch

    prep<<<(TOK * KTOT) / 256, 256, 0, stream>>>(inp, invp, bias, xp, out);
    sasut_gemm<<<512 * KSPLIT, 512, 0, stream>>>(xp, qw, fpw, alpha, noise, out);
}